// Round 3
// baseline (502.786 us; speedup 1.0000x reference)
//
#include <hip/hip_runtime.h>
#include <math.h>

typedef unsigned short u16;
typedef unsigned int   u32;
typedef short s16x8 __attribute__((ext_vector_type(8)));
typedef float f32x4 __attribute__((ext_vector_type(4)));

#define N_TOK 2048
#define DIM   512
#define HID   2048
#define NE    16
#define NG    4
#define EPG   4
#define MAXT  2048

#define BM 64
#define BN 128
#define BK 64
#define BSTRIDE 132   // u16; quad rows (8 apart) land 2-way on banks -> free (m136)
#define ASTRIDE 72    // u16; 144B rows, 16B-aligned for b128

// ---- workspace layout (bytes) ----
#define WS_CNT    0                          // 16 ints (zeroed each launch)
#define WS_OFF    128                        // 17 ints
#define WS_TOKIDX 256                        // 16*2048 ints -> ends 131328
#define WS_TW     (WS_TOKIDX + NE*MAXT*4)    // 2048*16 f32 -> ends 262400
#define WS_XB     (WS_TW + N_TOK*NE*4)       // 2048*512 u16 -> ends 2359552
#define WS_HBUF   (WS_XB + (size_t)N_TOK*DIM*2)  // 8192*2048 u16 (~33.5 MB)

__device__ __forceinline__ int* ws_i32(void* ws, size_t off) { return (int*)((char*)ws + off); }

__device__ __forceinline__ u16 f2b(float f) {   // fp32 -> bf16 RNE
    union { float f; u32 i; } v; v.f = f;
    u32 b = v.i;
    u32 r = b + 0x7FFFu + ((b >> 16) & 1u);
    return (u16)(r >> 16);
}

// ---------------- routing: one wave per token; also emits bf16 x ----------------
__global__ __launch_bounds__(64) void routing_kernel(
    const float* __restrict__ x, const float* __restrict__ Wr, const float* __restrict__ br,
    const float* __restrict__ Wgate, const float* __restrict__ bgate, void* ws)
{
    int t = blockIdx.x;
    int lane = threadIdx.x;

    float xl[8];
    {
        const float4* xr = (const float4*)(x + (size_t)t*DIM + lane*8);
        float4 a = xr[0], b = xr[1];
        xl[0]=a.x; xl[1]=a.y; xl[2]=a.z; xl[3]=a.w;
        xl[4]=b.x; xl[5]=b.y; xl[6]=b.z; xl[7]=b.w;
    }

    // emit bf16 x row for GEMM1 (16B store, aligned: (t*512+lane*8)*2)
    {
        union { u16 h[8]; uint4 q; } pk;
        #pragma unroll
        for (int i = 0; i < 8; i++) pk.h[i] = f2b(xl[i]);
        u16* xb = (u16*)((char*)ws + WS_XB);
        *(uint4*)(xb + (size_t)t*DIM + lane*8) = pk.q;
    }

    float gl[NG] = {0.f,0.f,0.f,0.f};
    float el[NE];
    #pragma unroll
    for (int e = 0; e < NE; e++) el[e] = 0.f;

    // Wr: [D][G] fp32 — row d = one float4
    {
        const float4* Wr4 = (const float4*)Wr;
        #pragma unroll
        for (int c = 0; c < 8; c++) {
            float4 w = Wr4[lane*8 + c];
            gl[0] += xl[c]*w.x; gl[1] += xl[c]*w.y;
            gl[2] += xl[c]*w.z; gl[3] += xl[c]*w.w;
        }
    }
    // Wgate: [G][D][EPG] fp32 — row (g,d) = one float4
    {
        const float4* Wg4 = (const float4*)Wgate;
        #pragma unroll
        for (int g = 0; g < NG; g++) {
            #pragma unroll
            for (int c = 0; c < 8; c++) {
                float4 w = Wg4[(size_t)g*DIM + lane*8 + c];
                el[g*4+0] += xl[c]*w.x; el[g*4+1] += xl[c]*w.y;
                el[g*4+2] += xl[c]*w.z; el[g*4+3] += xl[c]*w.w;
            }
        }
    }

    #pragma unroll
    for (int g = 0; g < NG; g++)
        #pragma unroll
        for (int s = 32; s; s >>= 1) gl[g] += __shfl_xor(gl[g], s);
    #pragma unroll
    for (int e = 0; e < NE; e++)
        #pragma unroll
        for (int s = 32; s; s >>= 1) el[e] += __shfl_xor(el[e], s);

    if (lane != 0) return;

    float gp[NG];
    float mx = -1e30f;
    #pragma unroll
    for (int g = 0; g < NG; g++) { gl[g] += br[g]; mx = fmaxf(mx, gl[g]); }
    float sum = 0.f;
    #pragma unroll
    for (int g = 0; g < NG; g++) { gp[g] = expf(gl[g] - mx); sum += gp[g]; }
    #pragma unroll
    for (int g = 0; g < NG; g++) gp[g] /= sum;

    int i0 = 0;
    #pragma unroll
    for (int g = 1; g < NG; g++) if (gp[g] > gp[i0]) i0 = g;
    int i1 = -1;
    #pragma unroll
    for (int g = 0; g < NG; g++) { if (g == i0) continue; if (i1 < 0 || gp[g] > gp[i1]) i1 = g; }

    bool act1 = (gp[i0] + gp[i1]) <= 0.9f;
    float mp0 = gp[i0], mp1 = act1 ? gp[i1] : 0.f;
    float inv = 1.f / (mp0 + mp1 + 1e-9f);
    float wg[NG] = {0.f,0.f,0.f,0.f};
    wg[i0] = mp0 * inv;
    wg[i1] = mp1 * inv;

    float tw[NE];
    #pragma unroll
    for (int g = 0; g < NG; g++) {
        float ep[EPG];
        float emx = -1e30f;
        #pragma unroll
        for (int j = 0; j < EPG; j++) {
            float v = el[g*4 + j] + bgate[g*4 + j];
            ep[j] = v; emx = fmaxf(emx, v);
        }
        float es = 0.f;
        #pragma unroll
        for (int j = 0; j < EPG; j++) { ep[j] = expf(ep[j] - emx); es += ep[j]; }
        #pragma unroll
        for (int j = 0; j < EPG; j++) ep[j] /= es;

        int j0 = 0;
        #pragma unroll
        for (int j = 1; j < EPG; j++) if (ep[j] > ep[j0]) j0 = j;
        int j1 = -1;
        #pragma unroll
        for (int j = 0; j < EPG; j++) { if (j == j0) continue; if (j1 < 0 || ep[j] > ep[j1]) j1 = j; }

        bool ea1 = (ep[j0] + ep[j1]) <= 0.9f;
        float e0 = ep[j0], e1 = ea1 ? ep[j1] : 0.f;
        float einv = 1.f / (e0 + e1 + 1e-9f);
        float we[EPG] = {0.f,0.f,0.f,0.f};
        we[j0] = e0 * einv;
        we[j1] = e1 * einv;
        #pragma unroll
        for (int j = 0; j < EPG; j++) tw[g*4 + j] = wg[g] * we[j] * 0.5f;   // SCALE = 1/sqrt(4)
    }

    float* twb = (float*)((char*)ws + WS_TW) + (size_t)t*NE;
    int*   cnt = ws_i32(ws, WS_CNT);
    int*   tok = ws_i32(ws, WS_TOKIDX);

    #pragma unroll
    for (int e = 0; e < NE; e++) {
        twb[e] = tw[e];
        if (tw[e] > 0.f) {
            int pos = atomicAdd(&cnt[e], 1);
            tok[e*MAXT + pos] = t;
        }
    }
}

// ---------------- prefix scan over 16 expert counts ----------------
__global__ void scan_kernel(void* ws)
{
    if (threadIdx.x == 0) {
        int* cnt = ws_i32(ws, WS_CNT);
        int* off = ws_i32(ws, WS_OFF);
        int s = 0;
        for (int e = 0; e < NE; e++) { off[e] = s; s += cnt[e]; }
        off[NE] = s;
    }
}

// ---------------- GEMM1: hbuf = bf16( silu(X W1) * (X W3) ) ----------------
__global__ __launch_bounds__(256) void gemm1_kernel(
    const float* __restrict__ W1, const float* __restrict__ W3, void* ws)
{
    int e  = blockIdx.z;
    const int* cnt = ws_i32(ws, WS_CNT);
    int ce = cnt[e];
    int m0 = blockIdx.y * BM;
    if (m0 >= ce) return;
    int n0 = blockIdx.x * BN;

    const int* off = ws_i32(ws, WS_OFF);
    const int* tok = ws_i32(ws, WS_TOKIDX) + e*MAXT;
    const u16* xb  = (const u16*)((char*)ws + WS_XB);
    u16* hbuf = (u16*)((char*)ws + WS_HBUF);
    int obase = off[e] + m0;

    __shared__ u16 As[BM*ASTRIDE];
    __shared__ u16 Bs0[BK*BSTRIDE];
    __shared__ u16 Bs1[BK*BSTRIDE];
    __shared__ int rowtok[BM];

    int tid = threadIdx.x;
    if (tid < BM) {
        int m = m0 + tid;
        rowtok[tid] = tok[m < ce ? m : (ce - 1)];
    }
    __syncthreads();

    int wave = tid >> 6, lane = tid & 63;
    int quad = lane >> 4, l16 = lane & 15;

    f32x4 acc1[4][2], acc3[4][2];
    #pragma unroll
    for (int mt = 0; mt < 4; mt++)
        #pragma unroll
        for (int nt = 0; nt < 2; nt++) {
            acc1[mt][nt] = (f32x4){0.f,0.f,0.f,0.f};
            acc3[mt][nt] = (f32x4){0.f,0.f,0.f,0.f};
        }

    const float* W1e = W1 + (size_t)e*DIM*HID;
    const float* W3e = W3 + (size_t)e*DIM*HID;

    for (int k0 = 0; k0 < DIM; k0 += BK) {
        // A: 64x64 bf16 from xb, 16B copies
        #pragma unroll
        for (int it = 0; it < 2; it++) {
            int idx = tid + it*256;
            int r = idx >> 3, seg = idx & 7;
            *(s16x8*)(&As[r*ASTRIDE + seg*8]) =
                *(const s16x8*)(xb + (size_t)rowtok[r]*DIM + k0 + seg*8);
        }
        // B: 64x128 fp32 -> bf16, per matrix 2048 float4 loads
        #pragma unroll
        for (int it = 0; it < 8; it++) {
            int idx = tid + it*256;
            int r = idx >> 5, seg = idx & 31;
            float4 v1 = *(const float4*)(W1e + (size_t)(k0+r)*HID + n0 + seg*4);
            float4 v3 = *(const float4*)(W3e + (size_t)(k0+r)*HID + n0 + seg*4);
            union { u16 h[4]; uint2 q; } p1, p3;
            p1.h[0]=f2b(v1.x); p1.h[1]=f2b(v1.y); p1.h[2]=f2b(v1.z); p1.h[3]=f2b(v1.w);
            p3.h[0]=f2b(v3.x); p3.h[1]=f2b(v3.y); p3.h[2]=f2b(v3.z); p3.h[3]=f2b(v3.w);
            *(uint2*)(&Bs0[r*BSTRIDE + seg*4]) = p1.q;
            *(uint2*)(&Bs1[r*BSTRIDE + seg*4]) = p3.q;
        }
        __syncthreads();

        #pragma unroll
        for (int kk = 0; kk < BK; kk += 32) {
            s16x8 af[4];
            #pragma unroll
            for (int mt = 0; mt < 4; mt++)
                af[mt] = *(const s16x8*)(&As[(mt*16 + l16)*ASTRIDE + kk + quad*8]);
            #pragma unroll
            for (int nt = 0; nt < 2; nt++) {
                int n = wave*32 + nt*16 + l16;
                s16x8 b1, b3;
                #pragma unroll
                for (int j = 0; j < 8; j++) {
                    int k = kk + quad*8 + j;
                    b1[j] = (short)Bs0[k*BSTRIDE + n];
                    b3[j] = (short)Bs1[k*BSTRIDE + n];
                }
                #pragma unroll
                for (int mt = 0; mt < 4; mt++) {
                    acc1[mt][nt] = __builtin_amdgcn_mfma_f32_16x16x32_bf16(af[mt], b1, acc1[mt][nt], 0, 0, 0);
                    acc3[mt][nt] = __builtin_amdgcn_mfma_f32_16x16x32_bf16(af[mt], b3, acc3[mt][nt], 0, 0, 0);
                }
            }
        }
        __syncthreads();
    }

    #pragma unroll
    for (int mt = 0; mt < 4; mt++) {
        #pragma unroll
        for (int r = 0; r < 4; r++) {
            int row = mt*16 + quad*4 + r;
            if (m0 + row < ce) {
                #pragma unroll
                for (int nt = 0; nt < 2; nt++) {
                    float a = acc1[mt][nt][r];
                    float b = acc3[mt][nt][r];
                    float h = (a / (1.f + expf(-a))) * b;
                    int col = wave*32 + nt*16 + l16;
                    hbuf[(size_t)(obase + row)*HID + n0 + col] = f2b(h);
                }
            }
        }
    }
}

// ---------------- GEMM2: out += tw * (h W2), fp32 atomics ----------------
__global__ __launch_bounds__(256) void gemm2_kernel(
    const float* __restrict__ W2, void* ws, float* __restrict__ out)
{
    int e  = blockIdx.z;
    const int* cnt = ws_i32(ws, WS_CNT);
    int ce = cnt[e];
    int m0 = blockIdx.y * BM;
    if (m0 >= ce) return;
    int n0 = blockIdx.x * BN;

    const int* off = ws_i32(ws, WS_OFF);
    const int* tok = ws_i32(ws, WS_TOKIDX) + e*MAXT;
    const float* twb = (const float*)((char*)ws + WS_TW);
    const u16* hbuf = (const u16*)((char*)ws + WS_HBUF);
    int abase = off[e] + m0;
    int total = off[NE];

    __shared__ u16 As[BM*ASTRIDE];
    __shared__ u16 Bs[BK*BSTRIDE];

    int tid = threadIdx.x;
    int wave = tid >> 6, lane = tid & 63;
    int quad = lane >> 4, l16 = lane & 15;

    f32x4 acc[4][2];
    #pragma unroll
    for (int mt = 0; mt < 4; mt++)
        #pragma unroll
        for (int nt = 0; nt < 2; nt++) acc[mt][nt] = (f32x4){0.f,0.f,0.f,0.f};

    const float* W2e = W2 + (size_t)e*HID*DIM;

    for (int k0 = 0; k0 < HID; k0 += BK) {
        #pragma unroll
        for (int it = 0; it < 2; it++) {
            int idx = tid + it*256;
            int r = idx >> 3, seg = idx & 7;
            int ar = abase + r;
            if (ar > total - 1) ar = total - 1;
            *(s16x8*)(&As[r*ASTRIDE + seg*8]) =
                *(const s16x8*)(hbuf + (size_t)ar*HID + k0 + seg*8);
        }
        #pragma unroll
        for (int it = 0; it < 8; it++) {
            int idx = tid + it*256;
            int r = idx >> 5, seg = idx & 31;
            float4 v = *(const float4*)(W2e + (size_t)(k0+r)*DIM + n0 + seg*4);
            union { u16 h[4]; uint2 q; } p;
            p.h[0]=f2b(v.x); p.h[1]=f2b(v.y); p.h[2]=f2b(v.z); p.h[3]=f2b(v.w);
            *(uint2*)(&Bs[r*BSTRIDE + seg*4]) = p.q;
        }
        __syncthreads();

        #pragma unroll
        for (int kk = 0; kk < BK; kk += 32) {
            s16x8 af[4];
            #pragma unroll
            for (int mt = 0; mt < 4; mt++)
                af[mt] = *(const s16x8*)(&As[(mt*16 + l16)*ASTRIDE + kk + quad*8]);
            #pragma unroll
            for (int nt = 0; nt < 2; nt++) {
                int n = wave*32 + nt*16 + l16;
                s16x8 bfr;
                #pragma unroll
                for (int j = 0; j < 8; j++) {
                    int k = kk + quad*8 + j;
                    bfr[j] = (short)Bs[k*BSTRIDE + n];
                }
                #pragma unroll
                for (int mt = 0; mt < 4; mt++)
                    acc[mt][nt] = __builtin_amdgcn_mfma_f32_16x16x32_bf16(af[mt], bfr, acc[mt][nt], 0, 0, 0);
            }
        }
        __syncthreads();
    }

    #pragma unroll
    for (int mt = 0; mt < 4; mt++) {
        #pragma unroll
        for (int r = 0; r < 4; r++) {
            int row = mt*16 + quad*4 + r;
            if (m0 + row < ce) {
                int t = tok[m0 + row];
                float s = twb[(size_t)t*NE + e];
                #pragma unroll
                for (int nt = 0; nt < 2; nt++) {
                    int col = wave*32 + nt*16 + l16;
                    atomicAdd(out + (size_t)t*DIM + n0 + col, acc[mt][nt][r] * s);
                }
            }
        }
    }
}

extern "C" void kernel_launch(void* const* d_in, const int* in_sizes, int n_in,
                              void* d_out, int out_size, void* d_ws, size_t ws_size,
                              hipStream_t stream)
{
    const float* x     = (const float*)d_in[0];
    const float* Wr    = (const float*)d_in[1];
    const float* br    = (const float*)d_in[2];
    const float* Wgate = (const float*)d_in[3];
    const float* bgate = (const float*)d_in[4];
    const float* W1    = (const float*)d_in[5];
    const float* W3    = (const float*)d_in[6];
    const float* W2    = (const float*)d_in[7];
    float* out = (float*)d_out;

    hipMemsetAsync(d_ws, 0, 256, stream);                       // expert counters
    hipMemsetAsync(d_out, 0, (size_t)out_size*sizeof(float), stream);  // atomic accum base

    routing_kernel<<<N_TOK, 64, 0, stream>>>(x, Wr, br, Wgate, bgate, d_ws);
    scan_kernel<<<1, 64, 0, stream>>>(d_ws);
    gemm1_kernel<<<dim3(HID/BN, N_TOK/BM, NE), 256, 0, stream>>>(W1, W3, d_ws);
    gemm2_kernel<<<dim3(DIM/BN, N_TOK/BM, NE), 256, 0, stream>>>(W2, d_ws, out);
}

// Round 4
// 471.057 us; speedup vs baseline: 1.0674x; 1.0674x over previous
//
#include <hip/hip_runtime.h>
#include <math.h>

typedef unsigned short u16;
typedef unsigned int   u32;
typedef short s16x8 __attribute__((ext_vector_type(8)));
typedef float f32x4 __attribute__((ext_vector_type(4)));

#define N_TOK 2048
#define DIM   512
#define HID   2048
#define NE    16
#define NG    4
#define EPG   4
#define MAXT  2048

#define BM 64
#define BN 128
#define BK 64
#define BSTRIDE 132   // fallback path
#define ASTRIDE 72    // fallback path

// ---- workspace layout (bytes) ----
#define WS_CNT    0                              // 16 ints (zeroed each launch)
#define WS_OFF    128                            // 17 ints
#define WS_TOKIDX 256                            // 16*2048 ints
#define WS_TW     (WS_TOKIDX + NE*MAXT*4)        // 2048*16 f32
#define WS_XB     (WS_TW + N_TOK*NE*4)           // 2048*512 u16 (bf16 x)
#define WS_HBUF   (WS_XB + (size_t)N_TOK*DIM*2)  // 8192*2048 u16
#define WS_W1T    (WS_HBUF + (size_t)8192*HID*2) // 16*2048*512 u16 (bf16 W1^T [e][n][k])
#define WS_W3T    (WS_W1T + (size_t)NE*HID*DIM*2)
#define WS_W2T    (WS_W3T + (size_t)NE*HID*DIM*2) // 16*512*2048 u16 (bf16 W2^T [e][n][k])
#define WS_NEED_FAST (WS_W2T + (size_t)NE*DIM*HID*2)

__device__ __forceinline__ int* ws_i32(void* ws, size_t off) { return (int*)((char*)ws + off); }

__device__ __forceinline__ u16 f2b(float f) {   // fp32 -> bf16 RNE
    union { float f; u32 i; } v; v.f = f;
    u32 b = v.i;
    u32 r = b + 0x7FFFu + ((b >> 16) & 1u);
    return (u16)(r >> 16);
}

// ---------------- routing: one wave per token; also emits bf16 x ----------------
__global__ __launch_bounds__(64) void routing_kernel(
    const float* __restrict__ x, const float* __restrict__ Wr, const float* __restrict__ br,
    const float* __restrict__ Wgate, const float* __restrict__ bgate, void* ws)
{
    int t = blockIdx.x;
    int lane = threadIdx.x;

    float xl[8];
    {
        const float4* xr = (const float4*)(x + (size_t)t*DIM + lane*8);
        float4 a = xr[0], b = xr[1];
        xl[0]=a.x; xl[1]=a.y; xl[2]=a.z; xl[3]=a.w;
        xl[4]=b.x; xl[5]=b.y; xl[6]=b.z; xl[7]=b.w;
    }

    {
        union { u16 h[8]; uint4 q; } pk;
        #pragma unroll
        for (int i = 0; i < 8; i++) pk.h[i] = f2b(xl[i]);
        u16* xb = (u16*)((char*)ws + WS_XB);
        *(uint4*)(xb + (size_t)t*DIM + lane*8) = pk.q;
    }

    float gl[NG] = {0.f,0.f,0.f,0.f};
    float el[NE];
    #pragma unroll
    for (int e = 0; e < NE; e++) el[e] = 0.f;

    {
        const float4* Wr4 = (const float4*)Wr;
        #pragma unroll
        for (int c = 0; c < 8; c++) {
            float4 w = Wr4[lane*8 + c];
            gl[0] += xl[c]*w.x; gl[1] += xl[c]*w.y;
            gl[2] += xl[c]*w.z; gl[3] += xl[c]*w.w;
        }
    }
    {
        const float4* Wg4 = (const float4*)Wgate;
        #pragma unroll
        for (int g = 0; g < NG; g++) {
            #pragma unroll
            for (int c = 0; c < 8; c++) {
                float4 w = Wg4[(size_t)g*DIM + lane*8 + c];
                el[g*4+0] += xl[c]*w.x; el[g*4+1] += xl[c]*w.y;
                el[g*4+2] += xl[c]*w.z; el[g*4+3] += xl[c]*w.w;
            }
        }
    }

    #pragma unroll
    for (int g = 0; g < NG; g++)
        #pragma unroll
        for (int s = 32; s; s >>= 1) gl[g] += __shfl_xor(gl[g], s);
    #pragma unroll
    for (int e = 0; e < NE; e++)
        #pragma unroll
        for (int s = 32; s; s >>= 1) el[e] += __shfl_xor(el[e], s);

    if (lane != 0) return;

    float gp[NG];
    float mx = -1e30f;
    #pragma unroll
    for (int g = 0; g < NG; g++) { gl[g] += br[g]; mx = fmaxf(mx, gl[g]); }
    float sum = 0.f;
    #pragma unroll
    for (int g = 0; g < NG; g++) { gp[g] = expf(gl[g] - mx); sum += gp[g]; }
    #pragma unroll
    for (int g = 0; g < NG; g++) gp[g] /= sum;

    int i0 = 0;
    #pragma unroll
    for (int g = 1; g < NG; g++) if (gp[g] > gp[i0]) i0 = g;
    int i1 = -1;
    #pragma unroll
    for (int g = 0; g < NG; g++) { if (g == i0) continue; if (i1 < 0 || gp[g] > gp[i1]) i1 = g; }

    bool act1 = (gp[i0] + gp[i1]) <= 0.9f;
    float mp0 = gp[i0], mp1 = act1 ? gp[i1] : 0.f;
    float inv = 1.f / (mp0 + mp1 + 1e-9f);
    float wg[NG] = {0.f,0.f,0.f,0.f};
    wg[i0] = mp0 * inv;
    wg[i1] = mp1 * inv;

    float tw[NE];
    #pragma unroll
    for (int g = 0; g < NG; g++) {
        float ep[EPG];
        float emx = -1e30f;
        #pragma unroll
        for (int j = 0; j < EPG; j++) {
            float v = el[g*4 + j] + bgate[g*4 + j];
            ep[j] = v; emx = fmaxf(emx, v);
        }
        float es = 0.f;
        #pragma unroll
        for (int j = 0; j < EPG; j++) { ep[j] = expf(ep[j] - emx); es += ep[j]; }
        #pragma unroll
        for (int j = 0; j < EPG; j++) ep[j] /= es;

        int j0 = 0;
        #pragma unroll
        for (int j = 1; j < EPG; j++) if (ep[j] > ep[j0]) j0 = j;
        int j1 = -1;
        #pragma unroll
        for (int j = 0; j < EPG; j++) { if (j == j0) continue; if (j1 < 0 || ep[j] > ep[j1]) j1 = j; }

        bool ea1 = (ep[j0] + ep[j1]) <= 0.9f;
        float e0 = ep[j0], e1 = ea1 ? ep[j1] : 0.f;
        float einv = 1.f / (e0 + e1 + 1e-9f);
        float we[EPG] = {0.f,0.f,0.f,0.f};
        we[j0] = e0 * einv;
        we[j1] = e1 * einv;
        #pragma unroll
        for (int j = 0; j < EPG; j++) tw[g*4 + j] = wg[g] * we[j] * 0.5f;   // SCALE = 1/sqrt(4)
    }

    float* twb = (float*)((char*)ws + WS_TW) + (size_t)t*NE;
    int*   cnt = ws_i32(ws, WS_CNT);
    int*   tok = ws_i32(ws, WS_TOKIDX);

    #pragma unroll
    for (int e = 0; e < NE; e++) {
        twb[e] = tw[e];
        if (tw[e] > 0.f) {
            int pos = atomicAdd(&cnt[e], 1);
            tok[e*MAXT + pos] = t;
        }
    }
}

__global__ void scan_kernel(void* ws)
{
    if (threadIdx.x == 0) {
        int* cnt = ws_i32(ws, WS_CNT);
        int* off = ws_i32(ws, WS_OFF);
        int s = 0;
        for (int e = 0; e < NE; e++) { off[e] = s; s += cnt[e]; }
        off[NE] = s;
    }
}

// ---------------- convert+transpose: src [e][K][N] fp32 -> dst [e][N][K] bf16 ----------------
__global__ __launch_bounds__(256) void transpose_cvt_kernel(
    const float* __restrict__ src, u16* __restrict__ dst, int K, int N)
{
    int e  = blockIdx.z;
    int n0 = blockIdx.x * 64;
    int k0 = blockIdx.y * 64;
    const float* s = src + (size_t)e*K*N;
    u16* d = dst + (size_t)e*N*K;

    __shared__ u16 T[64*72];   // [n][k], stride 72 u16
    int tid = threadIdx.x;

    #pragma unroll
    for (int it = 0; it < 4; it++) {
        int idx = tid + it*256;               // 1024 float4 loads (64 k-rows x 16)
        int kr = idx >> 4, nc = (idx & 15) * 4;
        float4 v = *(const float4*)(s + (size_t)(k0+kr)*N + n0 + nc);
        T[(nc+0)*72 + kr] = f2b(v.x);
        T[(nc+1)*72 + kr] = f2b(v.y);
        T[(nc+2)*72 + kr] = f2b(v.z);
        T[(nc+3)*72 + kr] = f2b(v.w);
    }
    __syncthreads();
    #pragma unroll
    for (int it = 0; it < 2; it++) {
        int idx = tid + it*256;               // 512 b128 stores (64 n-rows x 8)
        int nr = idx >> 3, sg = idx & 7;
        *(s16x8*)(d + (size_t)(n0+nr)*K + k0 + sg*8) = *(const s16x8*)(&T[nr*72 + sg*8]);
    }
}

// ---------------- FAST GEMM1: hbuf = bf16( silu(X W1) * (X W3) ), B^T bf16 input ----------------
__global__ __launch_bounds__(256) void gemm1_fast(void* ws)
{
    int e  = blockIdx.z;
    const int* cnt = ws_i32(ws, WS_CNT);
    int ce = cnt[e];
    int m0 = blockIdx.y * BM;
    if (m0 >= ce) return;
    int n0 = blockIdx.x * BN;

    const int* off = ws_i32(ws, WS_OFF);
    const int* tok = ws_i32(ws, WS_TOKIDX) + e*MAXT;
    const u16* xb  = (const u16*)((char*)ws + WS_XB);
    const u16* W1T = (const u16*)((char*)ws + WS_W1T) + (size_t)e*HID*DIM;  // [n][k]
    const u16* W3T = (const u16*)((char*)ws + WS_W3T) + (size_t)e*HID*DIM;
    u16* hbuf = (u16*)((char*)ws + WS_HBUF);
    int obase = off[e] + m0;

    __shared__ u16 As[BM*BK];        // swizzled [m][k]
    __shared__ u16 Bs0[BN*BK];       // swizzled [n][k]
    __shared__ u16 Bs1[BN*BK];
    __shared__ int rowtok[BM];

    int tid = threadIdx.x;
    if (tid < BM) {
        int m = m0 + tid;
        rowtok[tid] = tok[m < ce ? m : (ce - 1)];
    }
    __syncthreads();

    int wave = tid >> 6, lane = tid & 63;
    int quad = lane >> 4, l16 = lane & 15;
    int swz  = l16 & 7;

    f32x4 acc1[4][2], acc3[4][2];
    #pragma unroll
    for (int mt = 0; mt < 4; mt++)
        #pragma unroll
        for (int nt = 0; nt < 2; nt++) {
            acc1[mt][nt] = (f32x4){0.f,0.f,0.f,0.f};
            acc3[mt][nt] = (f32x4){0.f,0.f,0.f,0.f};
        }

    for (int k0 = 0; k0 < DIM; k0 += BK) {
        // A: 64 rows x 8 segs (swizzled b128 writes)
        #pragma unroll
        for (int it = 0; it < 2; it++) {
            int idx = tid + it*256;
            int r = idx >> 3, sg = idx & 7;
            *(s16x8*)(&As[r*BK + ((sg ^ (r & 7)) << 3)]) =
                *(const s16x8*)(xb + (size_t)rowtok[r]*DIM + k0 + sg*8);
        }
        // B: 128 rows x 8 segs per matrix
        #pragma unroll
        for (int it = 0; it < 4; it++) {
            int idx = tid + it*256;
            int r = idx >> 3, sg = idx & 7;
            int dst = r*BK + ((sg ^ (r & 7)) << 3);
            size_t srcoff = (size_t)(n0 + r)*DIM + k0 + sg*8;
            *(s16x8*)(&Bs0[dst]) = *(const s16x8*)(W1T + srcoff);
            *(s16x8*)(&Bs1[dst]) = *(const s16x8*)(W3T + srcoff);
        }
        __syncthreads();

        #pragma unroll
        for (int kk = 0; kk < BK; kk += 32) {
            int jj = (kk >> 3) + quad;           // k-segment 0..7
            int so = ((jj ^ swz) << 3);
            s16x8 af[4];
            #pragma unroll
            for (int mt = 0; mt < 4; mt++)
                af[mt] = *(const s16x8*)(&As[(mt*16 + l16)*BK + so]);
            #pragma unroll
            for (int nt = 0; nt < 2; nt++) {
                int n = wave*32 + nt*16 + l16;
                s16x8 b1 = *(const s16x8*)(&Bs0[n*BK + so]);
                s16x8 b3 = *(const s16x8*)(&Bs1[n*BK + so]);
                #pragma unroll
                for (int mt = 0; mt < 4; mt++) {
                    acc1[mt][nt] = __builtin_amdgcn_mfma_f32_16x16x32_bf16(af[mt], b1, acc1[mt][nt], 0, 0, 0);
                    acc3[mt][nt] = __builtin_amdgcn_mfma_f32_16x16x32_bf16(af[mt], b3, acc3[mt][nt], 0, 0, 0);
                }
            }
        }
        __syncthreads();
    }

    #pragma unroll
    for (int mt = 0; mt < 4; mt++) {
        #pragma unroll
        for (int r = 0; r < 4; r++) {
            int row = mt*16 + quad*4 + r;
            if (m0 + row < ce) {
                #pragma unroll
                for (int nt = 0; nt < 2; nt++) {
                    float a = acc1[mt][nt][r];
                    float b = acc3[mt][nt][r];
                    float h = (a / (1.f + expf(-a))) * b;
                    int col = wave*32 + nt*16 + l16;
                    hbuf[(size_t)(obase + row)*HID + n0 + col] = f2b(h);
                }
            }
        }
    }
}

// ---------------- FAST GEMM2: out += tw * (h W2), B^T bf16 input ----------------
__global__ __launch_bounds__(256) void gemm2_fast(void* ws, float* __restrict__ out)
{
    int e  = blockIdx.z;
    const int* cnt = ws_i32(ws, WS_CNT);
    int ce = cnt[e];
    int m0 = blockIdx.y * BM;
    if (m0 >= ce) return;
    int n0 = blockIdx.x * BN;

    const int* off = ws_i32(ws, WS_OFF);
    const int* tok = ws_i32(ws, WS_TOKIDX) + e*MAXT;
    const float* twb = (const float*)((char*)ws + WS_TW);
    const u16* hbuf = (const u16*)((char*)ws + WS_HBUF);
    const u16* W2T = (const u16*)((char*)ws + WS_W2T) + (size_t)e*DIM*HID;  // [n=512][k=2048]
    int abase = off[e] + m0;
    int total = off[NE];

    __shared__ u16 As[BM*BK];
    __shared__ u16 Bs[BN*BK];

    int tid = threadIdx.x;
    int wave = tid >> 6, lane = tid & 63;
    int quad = lane >> 4, l16 = lane & 15;
    int swz  = l16 & 7;

    f32x4 acc[4][2];
    #pragma unroll
    for (int mt = 0; mt < 4; mt++)
        #pragma unroll
        for (int nt = 0; nt < 2; nt++) acc[mt][nt] = (f32x4){0.f,0.f,0.f,0.f};

    for (int k0 = 0; k0 < HID; k0 += BK) {
        #pragma unroll
        for (int it = 0; it < 2; it++) {
            int idx = tid + it*256;
            int r = idx >> 3, sg = idx & 7;
            int ar = abase + r;
            if (ar > total - 1) ar = total - 1;
            *(s16x8*)(&As[r*BK + ((sg ^ (r & 7)) << 3)]) =
                *(const s16x8*)(hbuf + (size_t)ar*HID + k0 + sg*8);
        }
        #pragma unroll
        for (int it = 0; it < 4; it++) {
            int idx = tid + it*256;
            int r = idx >> 3, sg = idx & 7;
            *(s16x8*)(&Bs[r*BK + ((sg ^ (r & 7)) << 3)]) =
                *(const s16x8*)(W2T + (size_t)(n0 + r)*HID + k0 + sg*8);
        }
        __syncthreads();

        #pragma unroll
        for (int kk = 0; kk < BK; kk += 32) {
            int jj = (kk >> 3) + quad;
            int so = ((jj ^ swz) << 3);
            s16x8 af[4];
            #pragma unroll
            for (int mt = 0; mt < 4; mt++)
                af[mt] = *(const s16x8*)(&As[(mt*16 + l16)*BK + so]);
            #pragma unroll
            for (int nt = 0; nt < 2; nt++) {
                int n = wave*32 + nt*16 + l16;
                s16x8 bfr = *(const s16x8*)(&Bs[n*BK + so]);
                #pragma unroll
                for (int mt = 0; mt < 4; mt++)
                    acc[mt][nt] = __builtin_amdgcn_mfma_f32_16x16x32_bf16(af[mt], bfr, acc[mt][nt], 0, 0, 0);
            }
        }
        __syncthreads();
    }

    #pragma unroll
    for (int mt = 0; mt < 4; mt++) {
        #pragma unroll
        for (int r = 0; r < 4; r++) {
            int row = mt*16 + quad*4 + r;
            if (m0 + row < ce) {
                int t = tok[m0 + row];
                float s = twb[(size_t)t*NE + e];
                #pragma unroll
                for (int nt = 0; nt < 2; nt++) {
                    int col = wave*32 + nt*16 + l16;
                    atomicAdd(out + (size_t)t*DIM + n0 + col, acc[mt][nt][r] * s);
                }
            }
        }
    }
}

// ================= FALLBACK PATH (round-3, used if ws too small) =================
__global__ __launch_bounds__(256) void gemm1_kernel(
    const float* __restrict__ W1, const float* __restrict__ W3, void* ws)
{
    int e  = blockIdx.z;
    const int* cnt = ws_i32(ws, WS_CNT);
    int ce = cnt[e];
    int m0 = blockIdx.y * BM;
    if (m0 >= ce) return;
    int n0 = blockIdx.x * BN;

    const int* off = ws_i32(ws, WS_OFF);
    const int* tok = ws_i32(ws, WS_TOKIDX) + e*MAXT;
    const u16* xb  = (const u16*)((char*)ws + WS_XB);
    u16* hbuf = (u16*)((char*)ws + WS_HBUF);
    int obase = off[e] + m0;

    __shared__ u16 As[BM*ASTRIDE];
    __shared__ u16 Bs0[BK*BSTRIDE];
    __shared__ u16 Bs1[BK*BSTRIDE];
    __shared__ int rowtok[BM];

    int tid = threadIdx.x;
    if (tid < BM) {
        int m = m0 + tid;
        rowtok[tid] = tok[m < ce ? m : (ce - 1)];
    }
    __syncthreads();

    int wave = tid >> 6, lane = tid & 63;
    int quad = lane >> 4, l16 = lane & 15;

    f32x4 acc1[4][2], acc3[4][2];
    #pragma unroll
    for (int mt = 0; mt < 4; mt++)
        #pragma unroll
        for (int nt = 0; nt < 2; nt++) {
            acc1[mt][nt] = (f32x4){0.f,0.f,0.f,0.f};
            acc3[mt][nt] = (f32x4){0.f,0.f,0.f,0.f};
        }

    const float* W1e = W1 + (size_t)e*DIM*HID;
    const float* W3e = W3 + (size_t)e*DIM*HID;

    for (int k0 = 0; k0 < DIM; k0 += BK) {
        #pragma unroll
        for (int it = 0; it < 2; it++) {
            int idx = tid + it*256;
            int r = idx >> 3, seg = idx & 7;
            *(s16x8*)(&As[r*ASTRIDE + seg*8]) =
                *(const s16x8*)(xb + (size_t)rowtok[r]*DIM + k0 + seg*8);
        }
        #pragma unroll
        for (int it = 0; it < 8; it++) {
            int idx = tid + it*256;
            int r = idx >> 5, seg = idx & 31;
            float4 v1 = *(const float4*)(W1e + (size_t)(k0+r)*HID + n0 + seg*4);
            float4 v3 = *(const float4*)(W3e + (size_t)(k0+r)*HID + n0 + seg*4);
            union { u16 h[4]; uint2 q; } p1, p3;
            p1.h[0]=f2b(v1.x); p1.h[1]=f2b(v1.y); p1.h[2]=f2b(v1.z); p1.h[3]=f2b(v1.w);
            p3.h[0]=f2b(v3.x); p3.h[1]=f2b(v3.y); p3.h[2]=f2b(v3.z); p3.h[3]=f2b(v3.w);
            *(uint2*)(&Bs0[r*BSTRIDE + seg*4]) = p1.q;
            *(uint2*)(&Bs1[r*BSTRIDE + seg*4]) = p3.q;
        }
        __syncthreads();

        #pragma unroll
        for (int kk = 0; kk < BK; kk += 32) {
            s16x8 af[4];
            #pragma unroll
            for (int mt = 0; mt < 4; mt++)
                af[mt] = *(const s16x8*)(&As[(mt*16 + l16)*ASTRIDE + kk + quad*8]);
            #pragma unroll
            for (int nt = 0; nt < 2; nt++) {
                int n = wave*32 + nt*16 + l16;
                s16x8 b1, b3;
                #pragma unroll
                for (int j = 0; j < 8; j++) {
                    int k = kk + quad*8 + j;
                    b1[j] = (short)Bs0[k*BSTRIDE + n];
                    b3[j] = (short)Bs1[k*BSTRIDE + n];
                }
                #pragma unroll
                for (int mt = 0; mt < 4; mt++) {
                    acc1[mt][nt] = __builtin_amdgcn_mfma_f32_16x16x32_bf16(af[mt], b1, acc1[mt][nt], 0, 0, 0);
                    acc3[mt][nt] = __builtin_amdgcn_mfma_f32_16x16x32_bf16(af[mt], b3, acc3[mt][nt], 0, 0, 0);
                }
            }
        }
        __syncthreads();
    }

    #pragma unroll
    for (int mt = 0; mt < 4; mt++) {
        #pragma unroll
        for (int r = 0; r < 4; r++) {
            int row = mt*16 + quad*4 + r;
            if (m0 + row < ce) {
                #pragma unroll
                for (int nt = 0; nt < 2; nt++) {
                    float a = acc1[mt][nt][r];
                    float b = acc3[mt][nt][r];
                    float h = (a / (1.f + expf(-a))) * b;
                    int col = wave*32 + nt*16 + l16;
                    hbuf[(size_t)(obase + row)*HID + n0 + col] = f2b(h);
                }
            }
        }
    }
}

__global__ __launch_bounds__(256) void gemm2_kernel(
    const float* __restrict__ W2, void* ws, float* __restrict__ out)
{
    int e  = blockIdx.z;
    const int* cnt = ws_i32(ws, WS_CNT);
    int ce = cnt[e];
    int m0 = blockIdx.y * BM;
    if (m0 >= ce) return;
    int n0 = blockIdx.x * BN;

    const int* off = ws_i32(ws, WS_OFF);
    const int* tok = ws_i32(ws, WS_TOKIDX) + e*MAXT;
    const float* twb = (const float*)((char*)ws + WS_TW);
    const u16* hbuf = (const u16*)((char*)ws + WS_HBUF);
    int abase = off[e] + m0;
    int total = off[NE];

    __shared__ u16 As[BM*ASTRIDE];
    __shared__ u16 Bs[BK*BSTRIDE];

    int tid = threadIdx.x;
    int wave = tid >> 6, lane = tid & 63;
    int quad = lane >> 4, l16 = lane & 15;

    f32x4 acc[4][2];
    #pragma unroll
    for (int mt = 0; mt < 4; mt++)
        #pragma unroll
        for (int nt = 0; nt < 2; nt++) acc[mt][nt] = (f32x4){0.f,0.f,0.f,0.f};

    const float* W2e = W2 + (size_t)e*HID*DIM;

    for (int k0 = 0; k0 < HID; k0 += BK) {
        #pragma unroll
        for (int it = 0; it < 2; it++) {
            int idx = tid + it*256;
            int r = idx >> 3, seg = idx & 7;
            int ar = abase + r;
            if (ar > total - 1) ar = total - 1;
            *(s16x8*)(&As[r*ASTRIDE + seg*8]) =
                *(const s16x8*)(hbuf + (size_t)ar*HID + k0 + seg*8);
        }
        #pragma unroll
        for (int it = 0; it < 8; it++) {
            int idx = tid + it*256;
            int r = idx >> 5, seg = idx & 31;
            float4 v = *(const float4*)(W2e + (size_t)(k0+r)*DIM + n0 + seg*4);
            union { u16 h[4]; uint2 q; } p;
            p.h[0]=f2b(v.x); p.h[1]=f2b(v.y); p.h[2]=f2b(v.z); p.h[3]=f2b(v.w);
            *(uint2*)(&Bs[r*BSTRIDE + seg*4]) = p.q;
        }
        __syncthreads();

        #pragma unroll
        for (int kk = 0; kk < BK; kk += 32) {
            s16x8 af[4];
            #pragma unroll
            for (int mt = 0; mt < 4; mt++)
                af[mt] = *(const s16x8*)(&As[(mt*16 + l16)*ASTRIDE + kk + quad*8]);
            #pragma unroll
            for (int nt = 0; nt < 2; nt++) {
                int n = wave*32 + nt*16 + l16;
                s16x8 bfr;
                #pragma unroll
                for (int j = 0; j < 8; j++) {
                    int k = kk + quad*8 + j;
                    bfr[j] = (short)Bs[k*BSTRIDE + n];
                }
                #pragma unroll
                for (int mt = 0; mt < 4; mt++)
                    acc[mt][nt] = __builtin_amdgcn_mfma_f32_16x16x32_bf16(af[mt], bfr, acc[mt][nt], 0, 0, 0);
            }
        }
        __syncthreads();
    }

    #pragma unroll
    for (int mt = 0; mt < 4; mt++) {
        #pragma unroll
        for (int r = 0; r < 4; r++) {
            int row = mt*16 + quad*4 + r;
            if (m0 + row < ce) {
                int t = tok[m0 + row];
                float s = twb[(size_t)t*NE + e];
                #pragma unroll
                for (int nt = 0; nt < 2; nt++) {
                    int col = wave*32 + nt*16 + l16;
                    atomicAdd(out + (size_t)t*DIM + n0 + col, acc[mt][nt][r] * s);
                }
            }
        }
    }
}

extern "C" void kernel_launch(void* const* d_in, const int* in_sizes, int n_in,
                              void* d_out, int out_size, void* d_ws, size_t ws_size,
                              hipStream_t stream)
{
    const float* x     = (const float*)d_in[0];
    const float* Wr    = (const float*)d_in[1];
    const float* br    = (const float*)d_in[2];
    const float* Wgate = (const float*)d_in[3];
    const float* bgate = (const float*)d_in[4];
    const float* W1    = (const float*)d_in[5];
    const float* W3    = (const float*)d_in[6];
    const float* W2    = (const float*)d_in[7];
    float* out = (float*)d_out;

    hipMemsetAsync(d_ws, 0, 256, stream);
    hipMemsetAsync(d_out, 0, (size_t)out_size*sizeof(float), stream);

    routing_kernel<<<N_TOK, 64, 0, stream>>>(x, Wr, br, Wgate, bgate, d_ws);
    scan_kernel<<<1, 64, 0, stream>>>(d_ws);

    if (ws_size >= WS_NEED_FAST) {
        u16* w1t = (u16*)((char*)d_ws + WS_W1T);
        u16* w3t = (u16*)((char*)d_ws + WS_W3T);
        u16* w2t = (u16*)((char*)d_ws + WS_W2T);
        transpose_cvt_kernel<<<dim3(HID/64, DIM/64, NE), 256, 0, stream>>>(W1, w1t, DIM, HID);
        transpose_cvt_kernel<<<dim3(HID/64, DIM/64, NE), 256, 0, stream>>>(W3, w3t, DIM, HID);
        transpose_cvt_kernel<<<dim3(DIM/64, HID/64, NE), 256, 0, stream>>>(W2, w2t, HID, DIM);
        gemm1_fast<<<dim3(HID/BN, N_TOK/BM, NE), 256, 0, stream>>>(d_ws);
        gemm2_fast<<<dim3(DIM/BN, N_TOK/BM, NE), 256, 0, stream>>>(d_ws, out);
    } else {
        gemm1_kernel<<<dim3(HID/BN, N_TOK/BM, NE), 256, 0, stream>>>(W1, W3, d_ws);
        gemm2_kernel<<<dim3(DIM/BN, N_TOK/BM, NE), 256, 0, stream>>>(W2, d_ws, out);
    }
}

// Round 5
// 375.892 us; speedup vs baseline: 1.3376x; 1.2532x over previous
//
#include <hip/hip_runtime.h>
#include <math.h>

typedef unsigned short u16;
typedef unsigned int   u32;
typedef short s16x8 __attribute__((ext_vector_type(8)));
typedef float f32x4 __attribute__((ext_vector_type(4)));

#define N_TOK 2048
#define DIM   512
#define HID   2048
#define NE    16
#define NG    4
#define EPG   4
#define MAXT  2048

#define BM 64
#define BN 128
#define BK 64

// ---- workspace layout (bytes) ----
#define WS_CNT    0                              // 16 ints (written by expert_lists)
#define WS_OFF    128                            // 17 ints
#define WS_TOKIDX 256                            // 16*2048 ints
#define WS_TW     (WS_TOKIDX + NE*MAXT*4)        // twT[e][t]: 16*2048 f32
#define WS_XB     (WS_TW + N_TOK*NE*4)           // 2048*512 u16 (bf16 x)
#define WS_HBUF   (WS_XB + (size_t)N_TOK*DIM*2)  // 8192*2048 u16
#define WS_W1T    (WS_HBUF + (size_t)8192*HID*2) // 16*2048*512 u16 (bf16 W1^T [e][n][k])
#define WS_W3T    (WS_W1T + (size_t)NE*HID*DIM*2)
#define WS_W2T    (WS_W3T + (size_t)NE*HID*DIM*2) // 16*512*2048 u16 (bf16 W2^T [e][n][k])
#define WS_NEED_FAST (WS_W2T + (size_t)NE*DIM*HID*2)

__device__ __forceinline__ int* ws_i32(void* ws, size_t off) { return (int*)((char*)ws + off); }

__device__ __forceinline__ u16 f2b(float f) {   // fp32 -> bf16 RNE
    union { float f; u32 i; } v; v.f = f;
    u32 b = v.i;
    u32 r = b + 0x7FFFu + ((b >> 16) & 1u);
    return (u16)(r >> 16);
}

// ---------------- routing: one wave per token; writes twT + bf16 x; NO atomics ----------------
__global__ __launch_bounds__(64) void routing_kernel(
    const float* __restrict__ x, const float* __restrict__ Wr, const float* __restrict__ br,
    const float* __restrict__ Wgate, const float* __restrict__ bgate, void* ws)
{
    int t = blockIdx.x;
    int lane = threadIdx.x;

    float xl[8];
    {
        const float4* xr = (const float4*)(x + (size_t)t*DIM + lane*8);
        float4 a = xr[0], b = xr[1];
        xl[0]=a.x; xl[1]=a.y; xl[2]=a.z; xl[3]=a.w;
        xl[4]=b.x; xl[5]=b.y; xl[6]=b.z; xl[7]=b.w;
    }

    {
        union { u16 h[8]; uint4 q; } pk;
        #pragma unroll
        for (int i = 0; i < 8; i++) pk.h[i] = f2b(xl[i]);
        u16* xb = (u16*)((char*)ws + WS_XB);
        *(uint4*)(xb + (size_t)t*DIM + lane*8) = pk.q;
    }

    float gl[NG] = {0.f,0.f,0.f,0.f};
    float el[NE];
    #pragma unroll
    for (int e = 0; e < NE; e++) el[e] = 0.f;

    {
        const float4* Wr4 = (const float4*)Wr;
        #pragma unroll
        for (int c = 0; c < 8; c++) {
            float4 w = Wr4[lane*8 + c];
            gl[0] += xl[c]*w.x; gl[1] += xl[c]*w.y;
            gl[2] += xl[c]*w.z; gl[3] += xl[c]*w.w;
        }
    }
    {
        const float4* Wg4 = (const float4*)Wgate;
        #pragma unroll
        for (int g = 0; g < NG; g++) {
            #pragma unroll
            for (int c = 0; c < 8; c++) {
                float4 w = Wg4[(size_t)g*DIM + lane*8 + c];
                el[g*4+0] += xl[c]*w.x; el[g*4+1] += xl[c]*w.y;
                el[g*4+2] += xl[c]*w.z; el[g*4+3] += xl[c]*w.w;
            }
        }
    }

    #pragma unroll
    for (int g = 0; g < NG; g++)
        #pragma unroll
        for (int s = 32; s; s >>= 1) gl[g] += __shfl_xor(gl[g], s);
    #pragma unroll
    for (int e = 0; e < NE; e++)
        #pragma unroll
        for (int s = 32; s; s >>= 1) el[e] += __shfl_xor(el[e], s);

    if (lane != 0) return;

    float gp[NG];
    float mx = -1e30f;
    #pragma unroll
    for (int g = 0; g < NG; g++) { gl[g] += br[g]; mx = fmaxf(mx, gl[g]); }
    float sum = 0.f;
    #pragma unroll
    for (int g = 0; g < NG; g++) { gp[g] = expf(gl[g] - mx); sum += gp[g]; }
    #pragma unroll
    for (int g = 0; g < NG; g++) gp[g] /= sum;

    int i0 = 0;
    #pragma unroll
    for (int g = 1; g < NG; g++) if (gp[g] > gp[i0]) i0 = g;
    int i1 = -1;
    #pragma unroll
    for (int g = 0; g < NG; g++) { if (g == i0) continue; if (i1 < 0 || gp[g] > gp[i1]) i1 = g; }

    bool act1 = (gp[i0] + gp[i1]) <= 0.9f;
    float mp0 = gp[i0], mp1 = act1 ? gp[i1] : 0.f;
    float inv = 1.f / (mp0 + mp1 + 1e-9f);
    float wg[NG] = {0.f,0.f,0.f,0.f};
    wg[i0] = mp0 * inv;
    wg[i1] = mp1 * inv;

    float tw[NE];
    #pragma unroll
    for (int g = 0; g < NG; g++) {
        float ep[EPG];
        float emx = -1e30f;
        #pragma unroll
        for (int j = 0; j < EPG; j++) {
            float v = el[g*4 + j] + bgate[g*4 + j];
            ep[j] = v; emx = fmaxf(emx, v);
        }
        float es = 0.f;
        #pragma unroll
        for (int j = 0; j < EPG; j++) { ep[j] = expf(ep[j] - emx); es += ep[j]; }
        #pragma unroll
        for (int j = 0; j < EPG; j++) ep[j] /= es;

        int j0 = 0;
        #pragma unroll
        for (int j = 1; j < EPG; j++) if (ep[j] > ep[j0]) j0 = j;
        int j1 = -1;
        #pragma unroll
        for (int j = 0; j < EPG; j++) { if (j == j0) continue; if (j1 < 0 || ep[j] > ep[j1]) j1 = j; }

        bool ea1 = (ep[j0] + ep[j1]) <= 0.9f;
        float e0 = ep[j0], e1 = ea1 ? ep[j1] : 0.f;
        float einv = 1.f / (e0 + e1 + 1e-9f);
        float we[EPG] = {0.f,0.f,0.f,0.f};
        we[j0] = e0 * einv;
        we[j1] = e1 * einv;
        #pragma unroll
        for (int j = 0; j < EPG; j++) tw[g*4 + j] = wg[g] * we[j] * 0.5f;   // SCALE = 1/sqrt(4)
    }

    float* twT = (float*)((char*)ws + WS_TW);
    #pragma unroll
    for (int e = 0; e < NE; e++) twT[(size_t)e*N_TOK + t] = tw[e];
}

// ---------------- expert lists: ballot compaction, one wave per expert, no atomics ----------------
__global__ __launch_bounds__(64) void expert_lists_kernel(void* ws)
{
    int e = blockIdx.x;
    int lane = threadIdx.x;
    const float* twT = (const float*)((char*)ws + WS_TW) + (size_t)e*N_TOK;
    int* tok = ws_i32(ws, WS_TOKIDX) + e*MAXT;
    int* cnt = ws_i32(ws, WS_CNT);

    float v[32];
    #pragma unroll
    for (int r = 0; r < 32; r++) v[r] = twT[r*64 + lane];

    unsigned long long lanemask = (1ull << lane) - 1ull;
    int base = 0;
    #pragma unroll
    for (int r = 0; r < 32; r++) {
        bool a = v[r] > 0.f;
        unsigned long long m = __ballot(a);
        int pre = __popcll(m & lanemask);
        if (a) tok[base + pre] = r*64 + lane;
        base += __popcll(m);
    }
    if (lane == 0) cnt[e] = base;
}

__global__ void scan_kernel(void* ws)
{
    if (threadIdx.x == 0) {
        int* cnt = ws_i32(ws, WS_CNT);
        int* off = ws_i32(ws, WS_OFF);
        int s = 0;
        for (int e = 0; e < NE; e++) { off[e] = s; s += cnt[e]; }
        off[NE] = s;
    }
}

// ---------------- merged convert+transpose: fp32 [e][K][N] -> bf16 [e][N][K], 3 matrices ----------------
__global__ __launch_bounds__(256) void transpose_all_kernel(
    const float* __restrict__ W1, const float* __restrict__ W3,
    const float* __restrict__ W2, void* ws)
{
    int z = blockIdx.z;
    int mat = z >> 4, e = z & 15;
    const float* src; u16* dst; int K, N, k0, n0;
    if (mat == 0)      { src = W1; dst = (u16*)((char*)ws + WS_W1T); K = DIM; N = HID; n0 = blockIdx.x*64; k0 = blockIdx.y*64; }
    else if (mat == 1) { src = W3; dst = (u16*)((char*)ws + WS_W3T); K = DIM; N = HID; n0 = blockIdx.x*64; k0 = blockIdx.y*64; }
    else               { src = W2; dst = (u16*)((char*)ws + WS_W2T); K = HID; N = DIM; k0 = blockIdx.x*64; n0 = blockIdx.y*64; }

    const float* s = src + (size_t)e*K*N;
    u16* d = dst + (size_t)e*N*K;

    __shared__ u16 T[64*72];   // [n][k], stride 72 u16
    int tid = threadIdx.x;

    #pragma unroll
    for (int it = 0; it < 4; it++) {
        int idx = tid + it*256;               // 1024 float4 loads (64 k-rows x 16)
        int kr = idx >> 4, nc = (idx & 15) * 4;
        float4 v = *(const float4*)(s + (size_t)(k0+kr)*N + n0 + nc);
        T[(nc+0)*72 + kr] = f2b(v.x);
        T[(nc+1)*72 + kr] = f2b(v.y);
        T[(nc+2)*72 + kr] = f2b(v.z);
        T[(nc+3)*72 + kr] = f2b(v.w);
    }
    __syncthreads();
    #pragma unroll
    for (int it = 0; it < 2; it++) {
        int idx = tid + it*256;               // 512 b128 stores (64 n-rows x 8)
        int nr = idx >> 3, sg = idx & 7;
        *(s16x8*)(d + (size_t)(n0+nr)*K + k0 + sg*8) = *(const s16x8*)(&T[nr*72 + sg*8]);
    }
}

// ---------------- GEMM1: hbuf = bf16( silu(X W1) * (X W3) ), B^T bf16 input ----------------
__global__ __launch_bounds__(256) void gemm1_fast(void* ws)
{
    int e  = blockIdx.z;
    const int* cnt = ws_i32(ws, WS_CNT);
    int ce = cnt[e];
    int m0 = blockIdx.y * BM;
    if (m0 >= ce) return;
    int n0 = blockIdx.x * BN;

    const int* off = ws_i32(ws, WS_OFF);
    const int* tok = ws_i32(ws, WS_TOKIDX) + e*MAXT;
    const u16* xb  = (const u16*)((char*)ws + WS_XB);
    const u16* W1T = (const u16*)((char*)ws + WS_W1T) + (size_t)e*HID*DIM;  // [n][k]
    const u16* W3T = (const u16*)((char*)ws + WS_W3T) + (size_t)e*HID*DIM;
    u16* hbuf = (u16*)((char*)ws + WS_HBUF);
    int obase = off[e] + m0;

    __shared__ u16 As[BM*BK];        // swizzled [m][k]
    __shared__ u16 Bs0[BN*BK];       // swizzled [n][k]
    __shared__ u16 Bs1[BN*BK];
    __shared__ int rowtok[BM];

    int tid = threadIdx.x;
    if (tid < BM) {
        int m = m0 + tid;
        rowtok[tid] = tok[m < ce ? m : (ce - 1)];
    }
    __syncthreads();

    int wave = tid >> 6, lane = tid & 63;
    int quad = lane >> 4, l16 = lane & 15;
    int swz  = l16 & 7;

    f32x4 acc1[4][2], acc3[4][2];
    #pragma unroll
    for (int mt = 0; mt < 4; mt++)
        #pragma unroll
        for (int nt = 0; nt < 2; nt++) {
            acc1[mt][nt] = (f32x4){0.f,0.f,0.f,0.f};
            acc3[mt][nt] = (f32x4){0.f,0.f,0.f,0.f};
        }

    for (int k0 = 0; k0 < DIM; k0 += BK) {
        #pragma unroll
        for (int it = 0; it < 2; it++) {
            int idx = tid + it*256;
            int r = idx >> 3, sg = idx & 7;
            *(s16x8*)(&As[r*BK + ((sg ^ (r & 7)) << 3)]) =
                *(const s16x8*)(xb + (size_t)rowtok[r]*DIM + k0 + sg*8);
        }
        #pragma unroll
        for (int it = 0; it < 4; it++) {
            int idx = tid + it*256;
            int r = idx >> 3, sg = idx & 7;
            int dst = r*BK + ((sg ^ (r & 7)) << 3);
            size_t srcoff = (size_t)(n0 + r)*DIM + k0 + sg*8;
            *(s16x8*)(&Bs0[dst]) = *(const s16x8*)(W1T + srcoff);
            *(s16x8*)(&Bs1[dst]) = *(const s16x8*)(W3T + srcoff);
        }
        __syncthreads();

        #pragma unroll
        for (int kk = 0; kk < BK; kk += 32) {
            int jj = (kk >> 3) + quad;
            int so = ((jj ^ swz) << 3);
            s16x8 af[4];
            #pragma unroll
            for (int mt = 0; mt < 4; mt++)
                af[mt] = *(const s16x8*)(&As[(mt*16 + l16)*BK + so]);
            #pragma unroll
            for (int nt = 0; nt < 2; nt++) {
                int n = wave*32 + nt*16 + l16;
                s16x8 b1 = *(const s16x8*)(&Bs0[n*BK + so]);
                s16x8 b3 = *(const s16x8*)(&Bs1[n*BK + so]);
                #pragma unroll
                for (int mt = 0; mt < 4; mt++) {
                    acc1[mt][nt] = __builtin_amdgcn_mfma_f32_16x16x32_bf16(af[mt], b1, acc1[mt][nt], 0, 0, 0);
                    acc3[mt][nt] = __builtin_amdgcn_mfma_f32_16x16x32_bf16(af[mt], b3, acc3[mt][nt], 0, 0, 0);
                }
            }
        }
        __syncthreads();
    }

    #pragma unroll
    for (int mt = 0; mt < 4; mt++) {
        #pragma unroll
        for (int r = 0; r < 4; r++) {
            int row = mt*16 + quad*4 + r;
            if (m0 + row < ce) {
                #pragma unroll
                for (int nt = 0; nt < 2; nt++) {
                    float a = acc1[mt][nt][r];
                    float b = acc3[mt][nt][r];
                    float h = (a / (1.f + expf(-a))) * b;
                    int col = wave*32 + nt*16 + l16;
                    hbuf[(size_t)(obase + row)*HID + n0 + col] = f2b(h);
                }
            }
        }
    }
}

// ---------------- GEMM2: out += tw * (h W2), B^T bf16 input ----------------
__global__ __launch_bounds__(256) void gemm2_fast(void* ws, float* __restrict__ out)
{
    int e  = blockIdx.z;
    const int* cnt = ws_i32(ws, WS_CNT);
    int ce = cnt[e];
    int m0 = blockIdx.y * BM;
    if (m0 >= ce) return;
    int n0 = blockIdx.x * BN;

    const int* off = ws_i32(ws, WS_OFF);
    const int* tok = ws_i32(ws, WS_TOKIDX) + e*MAXT;
    const float* twT = (const float*)((char*)ws + WS_TW);
    const u16* hbuf = (const u16*)((char*)ws + WS_HBUF);
    const u16* W2T = (const u16*)((char*)ws + WS_W2T) + (size_t)e*DIM*HID;  // [n=512][k=2048]
    int abase = off[e] + m0;
    int total = off[NE];

    __shared__ u16 As[BM*BK];
    __shared__ u16 Bs[BN*BK];

    int tid = threadIdx.x;
    int wave = tid >> 6, lane = tid & 63;
    int quad = lane >> 4, l16 = lane & 15;
    int swz  = l16 & 7;

    f32x4 acc[4][2];
    #pragma unroll
    for (int mt = 0; mt < 4; mt++)
        #pragma unroll
        for (int nt = 0; nt < 2; nt++) acc[mt][nt] = (f32x4){0.f,0.f,0.f,0.f};

    for (int k0 = 0; k0 < HID; k0 += BK) {
        #pragma unroll
        for (int it = 0; it < 2; it++) {
            int idx = tid + it*256;
            int r = idx >> 3, sg = idx & 7;
            int ar = abase + r;
            if (ar > total - 1) ar = total - 1;
            *(s16x8*)(&As[r*BK + ((sg ^ (r & 7)) << 3)]) =
                *(const s16x8*)(hbuf + (size_t)ar*HID + k0 + sg*8);
        }
        #pragma unroll
        for (int it = 0; it < 4; it++) {
            int idx = tid + it*256;
            int r = idx >> 3, sg = idx & 7;
            *(s16x8*)(&Bs[r*BK + ((sg ^ (r & 7)) << 3)]) =
                *(const s16x8*)(W2T + (size_t)(n0 + r)*HID + k0 + sg*8);
        }
        __syncthreads();

        #pragma unroll
        for (int kk = 0; kk < BK; kk += 32) {
            int jj = (kk >> 3) + quad;
            int so = ((jj ^ swz) << 3);
            s16x8 af[4];
            #pragma unroll
            for (int mt = 0; mt < 4; mt++)
                af[mt] = *(const s16x8*)(&As[(mt*16 + l16)*BK + so]);
            #pragma unroll
            for (int nt = 0; nt < 2; nt++) {
                int n = wave*32 + nt*16 + l16;
                s16x8 bfr = *(const s16x8*)(&Bs[n*BK + so]);
                #pragma unroll
                for (int mt = 0; mt < 4; mt++)
                    acc[mt][nt] = __builtin_amdgcn_mfma_f32_16x16x32_bf16(af[mt], bfr, acc[mt][nt], 0, 0, 0);
            }
        }
        __syncthreads();
    }

    #pragma unroll
    for (int mt = 0; mt < 4; mt++) {
        #pragma unroll
        for (int r = 0; r < 4; r++) {
            int row = mt*16 + quad*4 + r;
            if (m0 + row < ce) {
                int t = tok[m0 + row];
                float s = twT[(size_t)e*N_TOK + t];
                #pragma unroll
                for (int nt = 0; nt < 2; nt++) {
                    int col = wave*32 + nt*16 + l16;
                    atomicAdd(out + (size_t)t*DIM + n0 + col, acc[mt][nt][r] * s);
                }
            }
        }
    }
}

extern "C" void kernel_launch(void* const* d_in, const int* in_sizes, int n_in,
                              void* d_out, int out_size, void* d_ws, size_t ws_size,
                              hipStream_t stream)
{
    const float* x     = (const float*)d_in[0];
    const float* Wr    = (const float*)d_in[1];
    const float* br    = (const float*)d_in[2];
    const float* Wgate = (const float*)d_in[3];
    const float* bgate = (const float*)d_in[4];
    const float* W1    = (const float*)d_in[5];
    const float* W3    = (const float*)d_in[6];
    const float* W2    = (const float*)d_in[7];
    float* out = (float*)d_out;

    hipMemsetAsync(d_out, 0, (size_t)out_size*sizeof(float), stream);

    transpose_all_kernel<<<dim3(32, 8, 48), 256, 0, stream>>>(W1, W3, W2, d_ws);
    routing_kernel<<<N_TOK, 64, 0, stream>>>(x, Wr, br, Wgate, bgate, d_ws);
    expert_lists_kernel<<<NE, 64, 0, stream>>>(d_ws);
    scan_kernel<<<1, 64, 0, stream>>>(d_ws);
    gemm1_fast<<<dim3(HID/BN, N_TOK/BM, NE), 256, 0, stream>>>(d_ws);
    gemm2_fast<<<dim3(DIM/BN, N_TOK/BM, NE), 256, 0, stream>>>(d_ws, out);
}

// Round 6
// 360.591 us; speedup vs baseline: 1.3943x; 1.0424x over previous
//
#include <hip/hip_runtime.h>
#include <math.h>

typedef unsigned short u16;
typedef unsigned int   u32;
typedef short s16x8 __attribute__((ext_vector_type(8)));
typedef float f32x4 __attribute__((ext_vector_type(4)));

#define N_TOK 2048
#define DIM   512
#define HID   2048
#define NE    16
#define NG    4
#define EPG   4
#define MAXT  2048

#define BM 64
#define BN 128
#define BK 64

// ---- workspace layout (bytes) ----
#define WS_CNT    0                              // 16 ints
#define WS_OFF    128                            // 17 ints
#define WS_TOKIDX 256                            // 16*2048 ints
#define WS_TW     (WS_TOKIDX + NE*MAXT*4)        // twT[e][t]: 16*2048 f32
#define WS_XB     (WS_TW + N_TOK*NE*4)           // 2048*512 u16 (bf16 x)
#define WS_HBUF   (WS_XB + (size_t)N_TOK*DIM*2)  // 8192*2048 u16
#define WS_W1T    (WS_HBUF + (size_t)8192*HID*2) // 16*2048*512 u16 (bf16 W1^T [e][n][k])
#define WS_W3T    (WS_W1T + (size_t)NE*HID*DIM*2)
#define WS_W2T    (WS_W3T + (size_t)NE*HID*DIM*2) // 16*512*2048 u16 (bf16 W2^T [e][n][k])

__device__ __forceinline__ int* ws_i32(void* ws, size_t off) { return (int*)((char*)ws + off); }

__device__ __forceinline__ u16 f2b(float f) {   // fp32 -> bf16 RNE
    union { float f; u32 i; } v; v.f = f;
    u32 b = v.i;
    u32 r = b + 0x7FFFu + ((b >> 16) & 1u);
    return (u16)(r >> 16);
}

// async global->LDS, 16B/lane; LDS side is wave-uniform base + lane*16
__device__ __forceinline__ void gl_lds16(const u16* g, u16* l) {
    __builtin_amdgcn_global_load_lds((const __attribute__((address_space(1))) void*)g,
                                     (__attribute__((address_space(3))) void*)l, 16, 0, 0);
}

// ---------------- routing: one wave per token; writes twT + bf16 x; NO atomics ----------------
__global__ __launch_bounds__(64) void routing_kernel(
    const float* __restrict__ x, const float* __restrict__ Wr, const float* __restrict__ br,
    const float* __restrict__ Wgate, const float* __restrict__ bgate, void* ws)
{
    int t = blockIdx.x;
    int lane = threadIdx.x;

    float xl[8];
    {
        const float4* xr = (const float4*)(x + (size_t)t*DIM + lane*8);
        float4 a = xr[0], b = xr[1];
        xl[0]=a.x; xl[1]=a.y; xl[2]=a.z; xl[3]=a.w;
        xl[4]=b.x; xl[5]=b.y; xl[6]=b.z; xl[7]=b.w;
    }

    {
        union { u16 h[8]; uint4 q; } pk;
        #pragma unroll
        for (int i = 0; i < 8; i++) pk.h[i] = f2b(xl[i]);
        u16* xb = (u16*)((char*)ws + WS_XB);
        *(uint4*)(xb + (size_t)t*DIM + lane*8) = pk.q;
    }

    float gl[NG] = {0.f,0.f,0.f,0.f};
    float el[NE];
    #pragma unroll
    for (int e = 0; e < NE; e++) el[e] = 0.f;

    {
        const float4* Wr4 = (const float4*)Wr;
        #pragma unroll
        for (int c = 0; c < 8; c++) {
            float4 w = Wr4[lane*8 + c];
            gl[0] += xl[c]*w.x; gl[1] += xl[c]*w.y;
            gl[2] += xl[c]*w.z; gl[3] += xl[c]*w.w;
        }
    }
    {
        const float4* Wg4 = (const float4*)Wgate;
        #pragma unroll
        for (int g = 0; g < NG; g++) {
            #pragma unroll
            for (int c = 0; c < 8; c++) {
                float4 w = Wg4[(size_t)g*DIM + lane*8 + c];
                el[g*4+0] += xl[c]*w.x; el[g*4+1] += xl[c]*w.y;
                el[g*4+2] += xl[c]*w.z; el[g*4+3] += xl[c]*w.w;
            }
        }
    }

    #pragma unroll
    for (int g = 0; g < NG; g++)
        #pragma unroll
        for (int s = 32; s; s >>= 1) gl[g] += __shfl_xor(gl[g], s);
    #pragma unroll
    for (int e = 0; e < NE; e++)
        #pragma unroll
        for (int s = 32; s; s >>= 1) el[e] += __shfl_xor(el[e], s);

    if (lane != 0) return;

    float gp[NG];
    float mx = -1e30f;
    #pragma unroll
    for (int g = 0; g < NG; g++) { gl[g] += br[g]; mx = fmaxf(mx, gl[g]); }
    float sum = 0.f;
    #pragma unroll
    for (int g = 0; g < NG; g++) { gp[g] = expf(gl[g] - mx); sum += gp[g]; }
    #pragma unroll
    for (int g = 0; g < NG; g++) gp[g] /= sum;

    int i0 = 0;
    #pragma unroll
    for (int g = 1; g < NG; g++) if (gp[g] > gp[i0]) i0 = g;
    int i1 = -1;
    #pragma unroll
    for (int g = 0; g < NG; g++) { if (g == i0) continue; if (i1 < 0 || gp[g] > gp[i1]) i1 = g; }

    bool act1 = (gp[i0] + gp[i1]) <= 0.9f;
    float mp0 = gp[i0], mp1 = act1 ? gp[i1] : 0.f;
    float inv = 1.f / (mp0 + mp1 + 1e-9f);
    float wg[NG] = {0.f,0.f,0.f,0.f};
    wg[i0] = mp0 * inv;
    wg[i1] = mp1 * inv;

    float tw[NE];
    #pragma unroll
    for (int g = 0; g < NG; g++) {
        float ep[EPG];
        float emx = -1e30f;
        #pragma unroll
        for (int j = 0; j < EPG; j++) {
            float v = el[g*4 + j] + bgate[g*4 + j];
            ep[j] = v; emx = fmaxf(emx, v);
        }
        float es = 0.f;
        #pragma unroll
        for (int j = 0; j < EPG; j++) { ep[j] = expf(ep[j] - emx); es += ep[j]; }
        #pragma unroll
        for (int j = 0; j < EPG; j++) ep[j] /= es;

        int j0 = 0;
        #pragma unroll
        for (int j = 1; j < EPG; j++) if (ep[j] > ep[j0]) j0 = j;
        int j1 = -1;
        #pragma unroll
        for (int j = 0; j < EPG; j++) { if (j == j0) continue; if (j1 < 0 || ep[j] > ep[j1]) j1 = j; }

        bool ea1 = (ep[j0] + ep[j1]) <= 0.9f;
        float e0 = ep[j0], e1 = ea1 ? ep[j1] : 0.f;
        float einv = 1.f / (e0 + e1 + 1e-9f);
        float we[EPG] = {0.f,0.f,0.f,0.f};
        we[j0] = e0 * einv;
        we[j1] = e1 * einv;
        #pragma unroll
        for (int j = 0; j < EPG; j++) tw[g*4 + j] = wg[g] * we[j] * 0.5f;   // SCALE = 1/sqrt(4)
    }

    float* twT = (float*)((char*)ws + WS_TW);
    #pragma unroll
    for (int e = 0; e < NE; e++) twT[(size_t)e*N_TOK + t] = tw[e];
}

// ---------------- expert lists + scan merged: 16 waves, ballot compaction ----------------
__global__ __launch_bounds__(1024) void expert_scan_kernel(void* ws)
{
    int tid = threadIdx.x;
    int e = tid >> 6, lane = tid & 63;
    const float* twT = (const float*)((char*)ws + WS_TW) + (size_t)e*N_TOK;
    int* tok = ws_i32(ws, WS_TOKIDX) + e*MAXT;
    __shared__ int scnt[NE];

    float v[32];
    #pragma unroll
    for (int r = 0; r < 32; r++) v[r] = twT[r*64 + lane];

    unsigned long long lanemask = (1ull << lane) - 1ull;
    int base = 0;
    #pragma unroll
    for (int r = 0; r < 32; r++) {
        bool a = v[r] > 0.f;
        unsigned long long m = __ballot(a);
        if (a) tok[base + __popcll(m & lanemask)] = r*64 + lane;
        base += __popcll(m);
    }
    if (lane == 0) scnt[e] = base;
    __syncthreads();
    if (tid == 0) {
        int* cnt = ws_i32(ws, WS_CNT);
        int* off = ws_i32(ws, WS_OFF);
        int s = 0;
        for (int i = 0; i < NE; i++) { cnt[i] = scnt[i]; off[i] = s; s += scnt[i]; }
        off[NE] = s;
    }
}

// ---------------- merged convert+transpose: fp32 [e][K][N] -> bf16 [e][N][K], 3 matrices ----------------
__global__ __launch_bounds__(256) void transpose_all_kernel(
    const float* __restrict__ W1, const float* __restrict__ W3,
    const float* __restrict__ W2, void* ws)
{
    int z = blockIdx.z;
    int mat = z >> 4, e = z & 15;
    const float* src; u16* dst; int K, N, k0, n0;
    if (mat == 0)      { src = W1; dst = (u16*)((char*)ws + WS_W1T); K = DIM; N = HID; n0 = blockIdx.x*64; k0 = blockIdx.y*64; }
    else if (mat == 1) { src = W3; dst = (u16*)((char*)ws + WS_W3T); K = DIM; N = HID; n0 = blockIdx.x*64; k0 = blockIdx.y*64; }
    else               { src = W2; dst = (u16*)((char*)ws + WS_W2T); K = HID; N = DIM; k0 = blockIdx.x*64; n0 = blockIdx.y*64; }

    const float* s = src + (size_t)e*K*N;
    u16* d = dst + (size_t)e*N*K;

    __shared__ u16 T[64*72];   // [n][k], stride 72 u16
    int tid = threadIdx.x;

    #pragma unroll
    for (int it = 0; it < 4; it++) {
        int idx = tid + it*256;               // 1024 float4 loads (64 k-rows x 16)
        int kr = idx >> 4, nc = (idx & 15) * 4;
        float4 v = *(const float4*)(s + (size_t)(k0+kr)*N + n0 + nc);
        T[(nc+0)*72 + kr] = f2b(v.x);
        T[(nc+1)*72 + kr] = f2b(v.y);
        T[(nc+2)*72 + kr] = f2b(v.z);
        T[(nc+3)*72 + kr] = f2b(v.w);
    }
    __syncthreads();
    #pragma unroll
    for (int it = 0; it < 2; it++) {
        int idx = tid + it*256;               // 512 b128 stores (64 n-rows x 8)
        int nr = idx >> 3, sg = idx & 7;
        *(s16x8*)(d + (size_t)(n0+nr)*K + k0 + sg*8) = *(const s16x8*)(&T[nr*72 + sg*8]);
    }
}

// ---------------- GEMM1: hbuf = bf16( silu(X W1) * (X W3) ), async-LDS staging ----------------
__global__ __launch_bounds__(256) void gemm1_fast(void* ws)
{
    int e  = blockIdx.z;
    const int* cnt = ws_i32(ws, WS_CNT);
    int ce = cnt[e];
    int m0 = blockIdx.y * BM;
    if (m0 >= ce) return;
    int n0 = blockIdx.x * BN;

    const int* off = ws_i32(ws, WS_OFF);
    const int* tok = ws_i32(ws, WS_TOKIDX) + e*MAXT;
    const u16* xb  = (const u16*)((char*)ws + WS_XB);
    const u16* W1T = (const u16*)((char*)ws + WS_W1T) + (size_t)e*HID*DIM;  // [n][k]
    const u16* W3T = (const u16*)((char*)ws + WS_W3T) + (size_t)e*HID*DIM;
    u16* hbuf = (u16*)((char*)ws + WS_HBUF);
    int obase = off[e] + m0;

    __shared__ u16 As[BM*BK];        // swizzled [m][k]
    __shared__ u16 Bs0[BN*BK];       // swizzled [n][k]
    __shared__ u16 Bs1[BN*BK];
    __shared__ int rowtok[BM];

    int tid = threadIdx.x;
    if (tid < BM) {
        int m = m0 + tid;
        rowtok[tid] = tok[m < ce ? m : (ce - 1)];
    }
    __syncthreads();

    int wave = tid >> 6, lane = tid & 63;
    int quad = lane >> 4, l16 = lane & 15;
    int swz  = l16 & 7;
    int r8 = lane >> 3, sg = lane & 7;
    int swk = ((sg ^ r8) << 3);      // swizzled k-offset (elements); tile-local row ≡ r8 (mod 8)

    // per-lane global row pointers for async staging (swizzle folded into global addr)
    const u16* arow0 = xb + (size_t)rowtok[wave*16 + r8]*DIM + swk;
    const u16* arow1 = xb + (size_t)rowtok[wave*16 + 8 + r8]*DIM + swk;
    const u16* b1row[4]; const u16* b3row[4];
    #pragma unroll
    for (int i = 0; i < 4; i++) {
        size_t nr = (size_t)(n0 + wave*32 + i*8 + r8)*DIM + swk;
        b1row[i] = W1T + nr;
        b3row[i] = W3T + nr;
    }

    f32x4 acc1[4][2], acc3[4][2];
    #pragma unroll
    for (int mt = 0; mt < 4; mt++)
        #pragma unroll
        for (int nt = 0; nt < 2; nt++) {
            acc1[mt][nt] = (f32x4){0.f,0.f,0.f,0.f};
            acc3[mt][nt] = (f32x4){0.f,0.f,0.f,0.f};
        }

    for (int k0 = 0; k0 < DIM; k0 += BK) {
        gl_lds16(arow0 + k0, &As[(wave*16)*BK]);
        gl_lds16(arow1 + k0, &As[(wave*16 + 8)*BK]);
        #pragma unroll
        for (int i = 0; i < 4; i++) {
            gl_lds16(b1row[i] + k0, &Bs0[(wave*32 + i*8)*BK]);
            gl_lds16(b3row[i] + k0, &Bs1[(wave*32 + i*8)*BK]);
        }
        __syncthreads();

        #pragma unroll
        for (int kk = 0; kk < BK; kk += 32) {
            int jj = (kk >> 3) + quad;
            int so = ((jj ^ swz) << 3);
            s16x8 af[4];
            #pragma unroll
            for (int mt = 0; mt < 4; mt++)
                af[mt] = *(const s16x8*)(&As[(mt*16 + l16)*BK + so]);
            #pragma unroll
            for (int nt = 0; nt < 2; nt++) {
                int n = wave*32 + nt*16 + l16;
                s16x8 b1 = *(const s16x8*)(&Bs0[n*BK + so]);
                s16x8 b3 = *(const s16x8*)(&Bs1[n*BK + so]);
                #pragma unroll
                for (int mt = 0; mt < 4; mt++) {
                    acc1[mt][nt] = __builtin_amdgcn_mfma_f32_16x16x32_bf16(af[mt], b1, acc1[mt][nt], 0, 0, 0);
                    acc3[mt][nt] = __builtin_amdgcn_mfma_f32_16x16x32_bf16(af[mt], b3, acc3[mt][nt], 0, 0, 0);
                }
            }
        }
        __syncthreads();
    }

    #pragma unroll
    for (int mt = 0; mt < 4; mt++) {
        #pragma unroll
        for (int r = 0; r < 4; r++) {
            int row = mt*16 + quad*4 + r;
            if (m0 + row < ce) {
                #pragma unroll
                for (int nt = 0; nt < 2; nt++) {
                    float a = acc1[mt][nt][r];
                    float b = acc3[mt][nt][r];
                    float h = (a / (1.f + expf(-a))) * b;
                    int col = wave*32 + nt*16 + l16;
                    hbuf[(size_t)(obase + row)*HID + n0 + col] = f2b(h);
                }
            }
        }
    }
}

// ---------------- GEMM2: out += tw * (h W2), async-LDS staging ----------------
__global__ __launch_bounds__(256) void gemm2_fast(void* ws, float* __restrict__ out)
{
    int e  = blockIdx.z;
    const int* cnt = ws_i32(ws, WS_CNT);
    int ce = cnt[e];
    int m0 = blockIdx.y * BM;
    if (m0 >= ce) return;
    int n0 = blockIdx.x * BN;

    const int* off = ws_i32(ws, WS_OFF);
    const int* tok = ws_i32(ws, WS_TOKIDX) + e*MAXT;
    const float* twT = (const float*)((char*)ws + WS_TW);
    const u16* hbuf = (const u16*)((char*)ws + WS_HBUF);
    const u16* W2T = (const u16*)((char*)ws + WS_W2T) + (size_t)e*DIM*HID;  // [n=512][k=2048]
    int abase = off[e] + m0;
    int total = off[NE];

    __shared__ u16 As[BM*BK];
    __shared__ u16 Bs[BN*BK];

    int tid = threadIdx.x;
    int wave = tid >> 6, lane = tid & 63;
    int quad = lane >> 4, l16 = lane & 15;
    int swz  = l16 & 7;
    int r8 = lane >> 3, sg = lane & 7;
    int swk = ((sg ^ r8) << 3);

    int ar0 = abase + wave*16 + r8;      if (ar0 > total - 1) ar0 = total - 1;
    int ar1 = abase + wave*16 + 8 + r8;  if (ar1 > total - 1) ar1 = total - 1;
    const u16* arow0 = hbuf + (size_t)ar0*HID + swk;
    const u16* arow1 = hbuf + (size_t)ar1*HID + swk;
    const u16* brow[4];
    #pragma unroll
    for (int i = 0; i < 4; i++)
        brow[i] = W2T + (size_t)(n0 + wave*32 + i*8 + r8)*HID + swk;

    f32x4 acc[4][2];
    #pragma unroll
    for (int mt = 0; mt < 4; mt++)
        #pragma unroll
        for (int nt = 0; nt < 2; nt++) acc[mt][nt] = (f32x4){0.f,0.f,0.f,0.f};

    for (int k0 = 0; k0 < HID; k0 += BK) {
        gl_lds16(arow0 + k0, &As[(wave*16)*BK]);
        gl_lds16(arow1 + k0, &As[(wave*16 + 8)*BK]);
        #pragma unroll
        for (int i = 0; i < 4; i++)
            gl_lds16(brow[i] + k0, &Bs[(wave*32 + i*8)*BK]);
        __syncthreads();

        #pragma unroll
        for (int kk = 0; kk < BK; kk += 32) {
            int jj = (kk >> 3) + quad;
            int so = ((jj ^ swz) << 3);
            s16x8 af[4];
            #pragma unroll
            for (int mt = 0; mt < 4; mt++)
                af[mt] = *(const s16x8*)(&As[(mt*16 + l16)*BK + so]);
            #pragma unroll
            for (int nt = 0; nt < 2; nt++) {
                int n = wave*32 + nt*16 + l16;
                s16x8 bfr = *(const s16x8*)(&Bs[n*BK + so]);
                #pragma unroll
                for (int mt = 0; mt < 4; mt++)
                    acc[mt][nt] = __builtin_amdgcn_mfma_f32_16x16x32_bf16(af[mt], bfr, acc[mt][nt], 0, 0, 0);
            }
        }
        __syncthreads();
    }

    #pragma unroll
    for (int mt = 0; mt < 4; mt++) {
        #pragma unroll
        for (int r = 0; r < 4; r++) {
            int row = mt*16 + quad*4 + r;
            if (m0 + row < ce) {
                int t = tok[m0 + row];
                float s = twT[(size_t)e*N_TOK + t];
                #pragma unroll
                for (int nt = 0; nt < 2; nt++) {
                    int col = wave*32 + nt*16 + l16;
                    atomicAdd(out + (size_t)t*DIM + n0 + col, acc[mt][nt][r] * s);
                }
            }
        }
    }
}

extern "C" void kernel_launch(void* const* d_in, const int* in_sizes, int n_in,
                              void* d_out, int out_size, void* d_ws, size_t ws_size,
                              hipStream_t stream)
{
    const float* x     = (const float*)d_in[0];
    const float* Wr    = (const float*)d_in[1];
    const float* br    = (const float*)d_in[2];
    const float* Wgate = (const float*)d_in[3];
    const float* bgate = (const float*)d_in[4];
    const float* W1    = (const float*)d_in[5];
    const float* W3    = (const float*)d_in[6];
    const float* W2    = (const float*)d_in[7];
    float* out = (float*)d_out;

    hipMemsetAsync(d_out, 0, (size_t)out_size*sizeof(float), stream);

    transpose_all_kernel<<<dim3(32, 8, 48), 256, 0, stream>>>(W1, W3, W2, d_ws);
    routing_kernel<<<N_TOK, 64, 0, stream>>>(x, Wr, br, Wgate, bgate, d_ws);
    expert_scan_kernel<<<1, 1024, 0, stream>>>(d_ws);
    gemm1_fast<<<dim3(HID/BN, N_TOK/BM, NE), 256, 0, stream>>>(d_ws);
    gemm2_fast<<<dim3(DIM/BN, N_TOK/BM, NE), 256, 0, stream>>>(d_ws, out);
}